// Round 17
// baseline (183.826 us; speedup 1.0000x reference)
//
#include <hip/hip_runtime.h>
#include <hip/hip_bf16.h>
#include <math.h>

// ---------------------------------------------------------------------------
// CrossModalAttention on MI355X (gfx950)
//   B=4, Cu=320, Cj=1024, H=W=64 (N=4096), ATTN_DIM=256, scale = 1/16
// Round 17: V-dedup attn. 896 thr = 14 waves: 4 QK (iw x jw, as R16) +
// 10 PV (pj x cg 64ch) where each PV wave accumulates BOTH iw outputs from
// ONE shared V-load set (o[2][2] = 64 AGPR, 4 V loads/iter vs 10).
// Per-iter L2 traffic drops 112KB -> 72KB (V read once). R16 sync skeleton.
// ---------------------------------------------------------------------------

typedef unsigned short u16;
typedef __attribute__((ext_vector_type(8))) short bf16x8;
typedef __attribute__((ext_vector_type(4))) float f32x4;
typedef __attribute__((ext_vector_type(16))) float f32x16;
typedef __attribute__((ext_vector_type(4))) unsigned short u16x4;

#define NB 4
#define CU 320
#define CJ 1024
#define NN 4096
#define AD 256

// ws layout (bytes)
#define XU_OFF 0u
#define XJ_OFF 10485760u
#define QB_OFF 44040192u
#define KB_OFF 52428800u
#define VB_OFF 60817408u
#define WQ_OFF 71303168u
#define WK_OFF 71467008u
#define WV_OFF 71991296u
#define WO_OFF 72646656u
#define AO_OFF XU_OFF

__device__ __forceinline__ u16 f2b(float f) {
    union { float f; unsigned u; } v; v.f = f;
    unsigned u = v.u;
    unsigned r = (u + 0x7fffu + ((u >> 16) & 1u)) >> 16;
    return (u16)r;
}

__device__ __forceinline__ float b2f(u16 x) {
    union { unsigned u; float f; } v; v.u = ((unsigned)x) << 16;
    return v.f;
}

__device__ __forceinline__ unsigned cvt_pk_bf16(float lo, float hi) {
    unsigned r;
    asm("v_cvt_pk_bf16_f32 %0, %1, %2" : "=v"(r) : "v"(lo), "v"(hi));
    return r;
}

__device__ __forceinline__ float exp2_fast(float x) {
    float r;
    asm("v_exp_f32 %0, %1" : "=v"(r) : "v"(x));
    return r;
}

__device__ __forceinline__ void async_cp16(const u16* g, char* l) {
    __builtin_amdgcn_global_load_lds(
        (const __attribute__((address_space(1))) unsigned int*)g,
        (__attribute__((address_space(3))) unsigned int*)l, 16, 0, 0);
}

// ---------------- weight cast ----------------
__global__ void wcast_kernel(const float* __restrict__ Wq, const float* __restrict__ Wk,
                             const float* __restrict__ Wv, const float* __restrict__ Wo,
                             u16* __restrict__ wq, u16* __restrict__ wk,
                             u16* __restrict__ wv, u16* __restrict__ wo) {
    int id = blockIdx.x * 256 + threadIdx.x;
    if (id < 81920) { wq[id] = f2b(Wq[id]); return; }
    id -= 81920;
    if (id < 262144) { wk[id] = f2b(Wk[id]); return; }
    id -= 262144;
    if (id < 327680) { wv[id] = f2b(Wv[id]); return; }
    id -= 327680;
    if (id < 102400) { wo[id] = f2b(Wo[id]); }
}

// ---------------- transpose [C][N] f32 -> [N][C] bf16 ----------------
__global__ __launch_bounds__(256) void transpose_cast_kernel(
        const float* __restrict__ in, u16* __restrict__ out, int C, int Nn) {
    __shared__ float tile[64][65];
    int b = blockIdx.z;
    int n0 = blockIdx.x * 64, c0 = blockIdx.y * 64;
    const float* src = in + (size_t)b * C * Nn;
    u16* dst = out + (size_t)b * Nn * C;
    int t = threadIdx.x;
    int nl = t & 63, cl = t >> 6;
    #pragma unroll
    for (int k = 0; k < 16; ++k) {
        int c = cl + k * 4;
        tile[c][nl] = src[(size_t)(c0 + c) * Nn + n0 + nl];
    }
    __syncthreads();
    int cl2 = t & 63, nl2 = t >> 6;
    #pragma unroll
    for (int k = 0; k < 16; ++k) {
        int n = nl2 + k * 4;
        dst[(size_t)(n0 + n) * C + c0 + cl2] = f2b(tile[cl2][n]);
    }
}

// ---------------- unified GEMM: out = A(16384xKD) @ W(NOUTxKD)^T ----------------
// EPI 0: bf16 out [M][NOUT], val=(acc+bias)*alpha            (Q)
// EPI 2: f32  out [b][o][n] transposed + bias + unet res     (final)
template <int EPI, int KD, int NOUT>
__global__ __launch_bounds__(256, 2) void gemm_kernel(
        const u16* __restrict__ A, const u16* __restrict__ W,
        const float* __restrict__ bias, void* __restrict__ outp,
        const float* __restrict__ unet, float alpha) {
    __shared__ __align__(16) char smem[49152];
    const int t = threadIdx.x;
    const int lane = t & 63, wave = t >> 6;
    const int r = lane & 15, h = lane >> 4;
    const int wr = wave >> 1, wc = wave & 1;
    const int m0 = blockIdx.x * 128;
    const int bn0 = blockIdx.y * 64;

    int goffA[4], goffB[2];
    #pragma unroll
    for (int n = 0; n < 4; ++n) {
        int c = n * 256 + t;
        int row = c >> 3, s = c & 7;
        goffA[n] = (m0 + row) * KD + ((s ^ (row & 7)) << 3);
    }
    #pragma unroll
    for (int n = 0; n < 2; ++n) {
        int c = n * 256 + t;
        int row = c >> 3, s = c & 7;
        goffB[n] = (bn0 + row) * KD + ((s ^ (row & 7)) << 3);
    }
    const unsigned wb = (unsigned)(t & ~63) * 16u;

    #define GSTAGE(BUF, KT) do {                                                  \
        _Pragma("unroll")                                                         \
        for (int n_ = 0; n_ < 4; ++n_)                                            \
            async_cp16(A + goffA[n_] + (KT) * 64,                                 \
                       smem + (BUF) * 24576 + n_ * 4096 + wb);                    \
        _Pragma("unroll")                                                         \
        for (int n_ = 0; n_ < 2; ++n_)                                            \
            async_cp16(W + goffB[n_] + (KT) * 64,                                 \
                       smem + (BUF) * 24576 + 16384 + n_ * 4096 + wb);            \
    } while (0)

    f32x4 acc[4][2];
    #pragma unroll
    for (int fr = 0; fr < 4; ++fr)
        #pragma unroll
        for (int fc = 0; fc < 2; ++fc) acc[fr][fc] = (f32x4)0.0f;

    GSTAGE(0, 0);
    int buf = 0;
    const int KS = KD / 64;
    for (int kt = 0; kt < KS; ++kt) {
        if (kt < KS - 1) {
            GSTAGE(buf ^ 1, kt + 1);
            asm volatile("s_waitcnt vmcnt(6)" ::: "memory");
        } else {
            asm volatile("s_waitcnt vmcnt(0)" ::: "memory");
        }
        __builtin_amdgcn_s_barrier();
        asm volatile("" ::: "memory");
        const char* Ab = smem + buf * 24576;
        const char* Bb = smem + buf * 24576 + 16384;
        #pragma unroll
        for (int kk = 0; kk < 2; ++kk) {
            bf16x8 af[4], bf[2];
            #pragma unroll
            for (int fr = 0; fr < 4; ++fr) {
                int row = wr * 64 + fr * 16 + r;
                af[fr] = *(const bf16x8*)(Ab + row * 128 + (((kk * 4 + h) ^ (row & 7)) << 4));
            }
            #pragma unroll
            for (int fc = 0; fc < 2; ++fc) {
                int rowb = wc * 32 + fc * 16 + r;
                bf[fc] = *(const bf16x8*)(Bb + rowb * 128 + (((kk * 4 + h) ^ (rowb & 7)) << 4));
            }
            #pragma unroll
            for (int fr = 0; fr < 4; ++fr)
                #pragma unroll
                for (int fc = 0; fc < 2; ++fc)
                    acc[fr][fc] = __builtin_amdgcn_mfma_f32_16x16x32_bf16(
                        af[fr], bf[fc], acc[fr][fc], 0, 0, 0);
        }
        asm volatile("" ::: "memory");
        __builtin_amdgcn_s_barrier();
        asm volatile("" ::: "memory");
        buf ^= 1;
    }
    #undef GSTAGE

    const int mw = m0 + wr * 64;
    const int ob0 = bn0 + wc * 32;

    if (EPI == 0) {
        u16* out = (u16*)outp;
        #pragma unroll
        for (int fc = 0; fc < 2; ++fc) {
            int o = ob0 + fc * 16 + r;
            float bs = bias[o];
            #pragma unroll
            for (int fr = 0; fr < 4; ++fr)
                #pragma unroll
                for (int rr = 0; rr < 4; ++rr) {
                    int mrow = mw + fr * 16 + h * 4 + rr;
                    out[(size_t)mrow * NOUT + o] = f2b((acc[fr][fc][rr] + bs) * alpha);
                }
        }
    } else {
        float* tile = (float*)(smem + wave * 8704);   // [32][68] f32
        #pragma unroll
        for (int fc = 0; fc < 2; ++fc)
            #pragma unroll
            for (int fr = 0; fr < 4; ++fr)
                *(f32x4*)(tile + (fc * 16 + r) * 68 + fr * 16 + h * 4) = acc[fr][fc];
        __builtin_amdgcn_s_waitcnt(0);
        float* out = (float*)outp;
        int bb = mw >> 12, nb = mw & 4095;
        #pragma unroll
        for (int g = 0; g < 8; ++g) {
            int chunk = g * 64 + lane;
            int row = chunk >> 4, ns = chunk & 15;
            int o = ob0 + row;
            size_t base = (size_t)bb * CU * NN + (size_t)o * NN + nb + ns * 4;
            f32x4 v = *(const f32x4*)(tile + row * 68 + ns * 4);
            f32x4 u = *(const f32x4*)(unet + base);
            float bs = bias[o];
            f32x4 res;
            #pragma unroll
            for (int rr = 0; rr < 4; ++rr) res[rr] = v[rr] + bs + u[rr];
            *(f32x4*)(out + base) = res;
        }
    }
}

// ---------------- fused K+V projection (KD=1024) ----------------
__global__ __launch_bounds__(256, 2) void gemm_kv_kernel(
        const u16* __restrict__ A, const u16* __restrict__ Wk,
        const u16* __restrict__ Wv, const float* __restrict__ bk,
        const float* __restrict__ bv, u16* __restrict__ Kb,
        u16* __restrict__ Vb) {
    const int KD = 1024;
    __shared__ __align__(16) char smem[49152];
    const int t = threadIdx.x;
    const int lane = t & 63, wave = t >> 6;
    const int r = lane & 15, h = lane >> 4;
    const int wr = wave >> 1, wc = wave & 1;
    const int m0 = blockIdx.x * 128;
    const bool isK = blockIdx.y < 4;
    const int bn0 = (isK ? blockIdx.y : (blockIdx.y - 4)) * 64;
    const u16* W = isK ? Wk : Wv;
    const float* bias = isK ? bk : bv;

    int goffA[4], goffB[2];
    #pragma unroll
    for (int n = 0; n < 4; ++n) {
        int c = n * 256 + t;
        int row = c >> 3, s = c & 7;
        goffA[n] = (m0 + row) * KD + ((s ^ (row & 7)) << 3);
    }
    #pragma unroll
    for (int n = 0; n < 2; ++n) {
        int c = n * 256 + t;
        int row = c >> 3, s = c & 7;
        goffB[n] = (bn0 + row) * KD + ((s ^ (row & 7)) << 3);
    }
    const unsigned wb = (unsigned)(t & ~63) * 16u;

    #define GSTAGE(BUF, KT) do {                                                  \
        _Pragma("unroll")                                                         \
        for (int n_ = 0; n_ < 4; ++n_)                                            \
            async_cp16(A + goffA[n_] + (KT) * 64,                                 \
                       smem + (BUF) * 24576 + n_ * 4096 + wb);                    \
        _Pragma("unroll")                                                         \
        for (int n_ = 0; n_ < 2; ++n_)                                            \
            async_cp16(W + goffB[n_] + (KT) * 64,                                 \
                       smem + (BUF) * 24576 + 16384 + n_ * 4096 + wb);            \
    } while (0)

    f32x4 acc[4][2];
    #pragma unroll
    for (int fr = 0; fr < 4; ++fr)
        #pragma unroll
        for (int fc = 0; fc < 2; ++fc) acc[fr][fc] = (f32x4)0.0f;

    GSTAGE(0, 0);
    int buf = 0;
    for (int kt = 0; kt < 16; ++kt) {
        if (kt < 15) {
            GSTAGE(buf ^ 1, kt + 1);
            asm volatile("s_waitcnt vmcnt(6)" ::: "memory");
        } else {
            asm volatile("s_waitcnt vmcnt(0)" ::: "memory");
        }
        __builtin_amdgcn_s_barrier();
        asm volatile("" ::: "memory");
        const char* Ab = smem + buf * 24576;
        const char* Bb = smem + buf * 24576 + 16384;
        #pragma unroll
        for (int kk = 0; kk < 2; ++kk) {
            bf16x8 af[4], bf[2];
            #pragma unroll
            for (int fr = 0; fr < 4; ++fr) {
                int row = wr * 64 + fr * 16 + r;
                af[fr] = *(const bf16x8*)(Ab + row * 128 + (((kk * 4 + h) ^ (row & 7)) << 4));
            }
            #pragma unroll
            for (int fc = 0; fc < 2; ++fc) {
                int rowb = wc * 32 + fc * 16 + r;
                bf[fc] = *(const bf16x8*)(Bb + rowb * 128 + (((kk * 4 + h) ^ (rowb & 7)) << 4));
            }
            #pragma unroll
            for (int fr = 0; fr < 4; ++fr)
                #pragma unroll
                for (int fc = 0; fc < 2; ++fc)
                    acc[fr][fc] = __builtin_amdgcn_mfma_f32_16x16x32_bf16(
                        af[fr], bf[fc], acc[fr][fc], 0, 0, 0);
        }
        asm volatile("" ::: "memory");
        __builtin_amdgcn_s_barrier();
        asm volatile("" ::: "memory");
        buf ^= 1;
    }
    #undef GSTAGE

    const int mw = m0 + wr * 64;
    const int ob0 = bn0 + wc * 32;

    if (isK) {
        #pragma unroll
        for (int fc = 0; fc < 2; ++fc) {
            int o = ob0 + fc * 16 + r;
            float bs = bias[o];
            #pragma unroll
            for (int fr = 0; fr < 4; ++fr)
                #pragma unroll
                for (int rr = 0; rr < 4; ++rr) {
                    int mrow = mw + fr * 16 + h * 4 + rr;
                    Kb[(size_t)mrow * AD + o] = f2b((acc[fr][fc][rr] + bs));
                }
        }
    } else {
        u16* tile = (u16*)(smem + wave * 4608);
        #pragma unroll
        for (int fc = 0; fc < 2; ++fc) {
            int o = ob0 + fc * 16 + r;
            float bs = bias[o];
            #pragma unroll
            for (int fr = 0; fr < 4; ++fr) {
                u16x4 v4;
                #pragma unroll
                for (int rr = 0; rr < 4; ++rr) v4[rr] = f2b(acc[fr][fc][rr] + bs);
                *(u16x4*)(tile + (fc * 16 + r) * 72 + fr * 16 + h * 4) = v4;
            }
        }
        __builtin_amdgcn_s_waitcnt(0);
        int bb = mw >> 12, nb = mw & 4095;
        #pragma unroll
        for (int g = 0; g < 4; ++g) {
            int chunk = g * 64 + lane;
            int row = chunk >> 3, ns = chunk & 7;
            int ch = ob0 + row;
            int j = nb + ns * 8;
            bf16x8 val = *(const bf16x8*)(tile + row * 72 + ns * 8);
            size_t off = (size_t)bb * CU * NN + (size_t)(ch >> 5) * (NN * 32)
                       + (size_t)(j >> 4) * 512
                       + (size_t)((ch & 31) + ((j >> 3) & 1) * 32) * 8 + (j & 7);
            *(bf16x8*)(Vb + off) = val;
        }
    }
}

// ---------------- flash attention (round-17: V-dedup, 14 waves) ------------
// Q: [B][N][256] bf16 (pre-scaled log2e/16), K: [B][N][256],
// V': [B][ct 10][j16 256][lane 64][8] bf16 (fragment order).
// 256 blocks x 896 thr (14 waves): waves 0-3 = QK (iw = w>>1, jw = w&1),
// waves 4-13 = PV (pj = pvid/5, cg = pvid%5 -> 2 ct tiles, BOTH iw:
// o[2 iw][2 ct] = 64 AGPR, one shared V-load set). K staged by PV waves 4-11.
// LDS 84,480 B: kbuf 2x32K @0; pbuf 2 par x 8960 @65536
//   (P frags [iw][jw] 4x2048 @+0, al @+8192, flags @+8704); ml @83456.
// Epilogue: in-place bf16 merge fb[64][328] @0 (aliases dead kbuf).
__global__ __launch_bounds__(896, 3) void attn_kernel(
        const u16* __restrict__ Q, const u16* __restrict__ K,
        const u16* __restrict__ V, u16* __restrict__ AO) {
    __shared__ __align__(16) char smem[84480];

    const int t = threadIdx.x;
    const int lane = t & 63;
    const int wave = t >> 6;          // 0..13
    const int r = lane & 31, hi = lane >> 5;

    int linear = blockIdx.x;
    int swz = (linear & 7) * 32 + (linear >> 3);
    int b = swz >> 6;
    int i0 = (swz & 63) * 64;

    const u16* Qb = Q + ((size_t)b * NN + i0) * AD;
    const u16* Kb = K + (size_t)b * NN * AD;
    const u16* Vb = V + (size_t)b * CU * NN;

    // ---- prologue: stage K[0] (2048 chunks) with all 896 threads ----
    {
        #pragma unroll
        for (int n = 0; n < 2; ++n) {
            int id = n * 896 + t;
            if (id < 2048) {
                int row = (id >> 5) & 63, c16 = id & 31;
                async_cp16(Kb + row * 256 + ((c16 ^ (row & 31)) << 3),
                           smem + (unsigned)(n * 896 + (t & ~63)) * 16u);
            }
        }
        if (t < 256) {
            int id = 1792 + t;
            int row = (id >> 5) & 63, c16 = id & 31;
            async_cp16(Kb + row * 256 + ((c16 ^ (row & 31)) << 3),
                       smem + (unsigned)(1792 + (t & ~63)) * 16u);
        }
    }
    asm volatile("s_waitcnt vmcnt(0)" ::: "memory");
    __builtin_amdgcn_s_barrier();     // K[0] ready
    asm volatile("" ::: "memory");

    if (wave < 4) {
        // ================= QK role (q hoisted, no staging, no vmcnt) =========
        const int iw = wave >> 1;
        const int jw = wave & 1;
        bf16x8 q[16];
        #pragma unroll
        for (int kk = 0; kk < 16; ++kk)
            q[kk] = *(const bf16x8*)(Qb + (size_t)(iw * 32 + r) * AD + kk * 16 + hi * 8);
        float m = -INFINITY, lsum = 0.0f;

        for (int i = 0; i < 64; ++i) {
            if (i) {
                __builtin_amdgcn_s_barrier();      // K[i] staged by PV waves
                asm volatile("" ::: "memory");
            }
            const char* Kt = smem + (i & 1) * 32768 + jw * 16384;
            f32x16 sa = (f32x16)0.0f, sb = (f32x16)0.0f;
            __builtin_amdgcn_s_setprio(1);
            #pragma unroll
            for (int kk = 0; kk < 8; ++kk) {
                bf16x8 k0 = *(const bf16x8*)(Kt + r * 512 + (((2 * kk + hi) ^ r) << 4));
                bf16x8 k1 = *(const bf16x8*)(Kt + r * 512 + (((2 * (kk + 8) + hi) ^ r) << 4));
                sa = __builtin_amdgcn_mfma_f32_32x32x16_bf16(k0, q[kk], sa, 0, 0, 0);
                sb = __builtin_amdgcn_mfma_f32_32x32x16_bf16(k1, q[kk + 8], sb, 0, 0, 0);
            }
            __builtin_amdgcn_s_setprio(0);
            f32x16 s = sa + sb;

            // softmax (exp2 domain, defer-max THR=8)
            float x0 = fmaxf(s[0], s[1]),   x1 = fmaxf(s[2], s[3]);
            float x2 = fmaxf(s[4], s[5]),   x3 = fmaxf(s[6], s[7]);
            float x4 = fmaxf(s[8], s[9]),   x5 = fmaxf(s[10], s[11]);
            float x6 = fmaxf(s[12], s[13]), x7 = fmaxf(s[14], s[15]);
            float pmax = fmaxf(fmaxf(fmaxf(x0, x1), fmaxf(x2, x3)),
                               fmaxf(fmaxf(x4, x5), fmaxf(x6, x7)));
            pmax = fmaxf(pmax, __shfl_xor(pmax, 32));
            char* pb = smem + 65536 + (i & 1) * 8960;
            int fl = __any(pmax > m + 8.0f) ? 1 : 0;
            if (fl) {
                float mn = fmaxf(m, pmax);
                float al = exp2_fast(m - mn);
                m = mn;
                lsum *= al;
                if (lane < 32) *(float*)(pb + 8192 + (iw * 2 + jw) * 128 + r * 4) = al;
            }
            if (lane == 0) *(int*)(pb + 8704 + (iw * 2 + jw) * 4) = fl;
            float p[16];
            #pragma unroll
            for (int e = 0; e < 16; ++e) p[e] = exp2_fast(s[e] - m);
            float y0 = (p[0] + p[1]) + (p[2] + p[3]);
            float y1 = (p[4] + p[5]) + (p[6] + p[7]);
            float y2 = (p[8] + p[9]) + (p[10] + p[11]);
            float y3 = (p[12] + p[13]) + (p[14] + p[15]);
            float ps = (y0 + y1) + (y2 + y3);
            ps += __shfl_xor(ps, 32);
            lsum += ps;

            // P -> B-operand fragments, publish to pbuf[par][iw][jw]
            #pragma unroll
            for (int ks = 0; ks < 2; ++ks) {
                unsigned a0 = cvt_pk_bf16(p[8 * ks + 0], p[8 * ks + 1]);
                unsigned a1 = cvt_pk_bf16(p[8 * ks + 2], p[8 * ks + 3]);
                unsigned b0 = cvt_pk_bf16(p[8 * ks + 4], p[8 * ks + 5]);
                unsigned b1 = cvt_pk_bf16(p[8 * ks + 6], p[8 * ks + 7]);
                asm("v_permlane32_swap_b32 %0, %1" : "+v"(a0), "+v"(b0));
                asm("v_permlane32_swap_b32 %0, %1" : "+v"(a1), "+v"(b1));
                union { unsigned w[4]; bf16x8 v; } u;
                u.w[0] = a0; u.w[1] = a1; u.w[2] = b0; u.w[3] = b1;
                *(bf16x8*)(pb + (iw * 2 + jw) * 2048 + ks * 1024 + lane * 16) = u.v;
            }
            asm volatile("s_waitcnt lgkmcnt(0)" ::: "memory");
            __builtin_amdgcn_sched_barrier(0);
        }
        __builtin_amdgcn_s_barrier();   // P(63) published
        asm volatile("" ::: "memory");
        if (lane < 32) {
            *(float*)(smem + 83456 + (iw * 2 + jw) * 128 + r * 4) = m;
            *(float*)(smem + 83456 + 512 + (iw * 2 + jw) * 128 + r * 4) = lsum;
        }
        __syncthreads();    // syncA
        __syncthreads();    // syncB
        __syncthreads();    // syncC
    } else {
        // ================= PV role (V read ONCE, both iw accumulated) ========
        const int pvid = wave - 4;          // 0..9
        const int pj = pvid / 5;            // which jw's P
        const int cg = pvid % 5;            // 2 ct tiles: cg*2, cg*2+1
        const int tp = t - 256;             // 0..639; stagers are tp<512

        // K staging map: 2048 chunks of 16B over 512 threads (waves 4-11)
        int goffp[4];
        #pragma unroll
        for (int n = 0; n < 4; ++n) {
            int id = n * 512 + tp;
            int row = (id >> 5) & 63;
            int c16 = id & 31;
            goffp[n] = row * 256 + ((c16 ^ (row & 31)) << 3);
        }
        const unsigned wbp = (unsigned)(tp & ~63) * 16u;

        #define STAGE(BUF, KP) do {                                               \
            if (tp < 512) {                                                       \
                _Pragma("unroll")                                                 \
                for (int n_ = 0; n_ < 4; ++n_)                                    \
                    async_cp16((KP) + goffp[n_],                                  \
                               smem + (BUF) * 32768 + n_ * 8192 + wbp);           \
            }                                                                     \
        } while (0)

        f32x16 o[2][2];
        #pragma unroll
        for (int iw = 0; iw < 2; ++iw)
            #pragma unroll
            for (int ct = 0; ct < 2; ++ct) o[iw][ct] = (f32x16)0.0f;
        const u16* vb = Vb + (size_t)(cg * 2) * 131072 + lane * 8;

        #define PV_BODY(TI) do {                                                  \
            const char* pb = smem + 65536 + ((TI) & 1) * 8960;                    \
            int fl0 = *(volatile const int*)(pb + 8704 + (0 * 2 + pj) * 4);       \
            int fl1 = *(volatile const int*)(pb + 8704 + (1 * 2 + pj) * 4);       \
            bf16x8 pf00 = *(const bf16x8*)(pb + (0 * 2 + pj) * 2048 + lane * 16); \
            bf16x8 pf01 = *(const bf16x8*)(pb + (0 * 2 + pj) * 2048 + 1024 +      \
                                           lane * 16);                            \
            bf16x8 pf10 = *(const bf16x8*)(pb + (1 * 2 + pj) * 2048 + lane * 16); \
            bf16x8 pf11 = *(const bf16x8*)(pb + (1 * 2 + pj) * 2048 + 1024 +      \
                                           lane * 16);                            \
            bf16x8 v00 = *(const bf16x8*)(vb + ((TI) * 4 + pj * 2 + 0) * 512);    \
            bf16x8 v01 = *(const bf16x8*)(vb + ((TI) * 4 + pj * 2 + 1) * 512);    \
            bf16x8 v10 = *(const bf16x8*)(vb + 131072 +                           \
                                          ((TI) * 4 + pj * 2 + 0) * 512);         \
            bf16x8 v11 = *(const bf16x8*)(vb + 131072 +                           \
                                          ((TI) * 4 + pj * 2 + 1) * 512);         \
            if (fl0) {                                                            \
                float alv = *(volatile const float*)(pb + 8192 +                  \
                                (0 * 2 + pj) * 128 + (lane & 31) * 4);            \
                o[0][0] *= alv; o[0][1] *= alv;                                   \
            }                                                                     \
            if (fl1) {                                                            \
                float alv = *(volatile const float*)(pb + 8192 +                  \
                                (1 * 2 + pj) * 128 + (lane & 31) * 4);            \
                o[1][0] *= alv; o[1][1] *= alv;                                   \
            }                                                                     \
            __builtin_amdgcn_s_setprio(1);                                        \
            o[0][0] = __builtin_amdgcn_mfma_f32_32x32x16_bf16(v00, pf00, o[0][0], 0, 0, 0); \
            o[0][1] = __builtin_amdgcn_mfma_f32_32x32x16_bf16(v10, pf00, o[0][1], 0, 0, 0); \
            o[1][0] = __builtin_amdgcn_mfma_f32_32x32x16_bf16(v00, pf10, o[1][0], 0, 0, 0); \
            o[1][1] = __builtin_amdgcn_mfma_f32_32x32x16_bf16(v10, pf10, o[1][1], 0, 0, 0); \
            o[0][0] = __builtin_amdgcn_mfma_f32_32x32x16_bf16(v01, pf01, o[0][0], 0, 0, 0); \
            o[0][1] = __builtin_amdgcn_mfma_f32_32x32x16_bf16(v11, pf01, o[0][1], 0, 0, 0); \
            o[1][0] = __builtin_amdgcn_mfma_f32_32x32x16_bf16(v01, pf11, o[1][0], 0, 0, 0); \
            o[1][1] = __builtin_amdgcn_mfma_f32_32x32x16_bf16(v11, pf11, o[1][1], 0, 0, 0); \
            __builtin_amdgcn_s_setprio(0);                                        \
        } while (0)

        for (int i = 0; i < 64; ++i) {
            if (i) {
                __builtin_amdgcn_s_barrier();
                asm volatile("" ::: "memory");
            }
            if (i < 63) STAGE((i + 1) & 1, Kb + (i + 1) * 16384);
            if (i >= 1) PV_BODY(i - 1);
            asm volatile("s_waitcnt vmcnt(0)" ::: "memory");
        }
        __builtin_amdgcn_s_barrier();   // P(63) published
        asm volatile("" ::: "memory");
        PV_BODY(63);

        __syncthreads();    // syncA: m/l published, kbuf dead
        float fsc[2], inv[2];
        #pragma unroll
        for (int iw = 0; iw < 2; ++iw) {
            float m0 = *(const float*)(smem + 83456 + (iw * 2 + pj) * 128 + r * 4);
            float l0 = *(const float*)(smem + 83456 + 512 + (iw * 2 + pj) * 128 + r * 4);
            float m1 = *(const float*)(smem + 83456 + (iw * 2 + (pj ^ 1)) * 128 + r * 4);
            float l1 = *(const float*)(smem + 83456 + 512 + (iw * 2 + (pj ^ 1)) * 128 + r * 4);
            float M = fmaxf(m0, m1);
            float f0 = exp2_fast(m0 - M);
            float f1 = exp2_fast(m1 - M);
            fsc[iw] = f0;
            inv[iw] = 1.0f / (l0 * f0 + l1 * f1);
        }

        u16* fb = (u16*)smem;              // [64][328] bf16, in-place merge
        if (pj == 1) {
            #pragma unroll
            for (int iw = 0; iw < 2; ++iw)
                #pragma unroll
                for (int ct = 0; ct < 2; ++ct)
                    #pragma unroll
                    for (int e = 0; e < 16; ++e) {
                        int c = cg * 64 + ct * 32 + (e & 3) + 8 * (e >> 2) + 4 * hi;
                        fb[(iw * 32 + r) * 328 + c] = f2b(o[iw][ct][e] * fsc[iw]);
                    }
        }
        __syncthreads();    // syncB
        if (pj == 0) {
            #pragma unroll
            for (int iw = 0; iw < 2; ++iw)
                #pragma unroll
                for (int ct = 0; ct < 2; ++ct)
                    #pragma unroll
                    for (int g = 0; g < 4; ++g) {
                        int cb = cg * 64 + ct * 32 + 8 * g + 4 * hi;
                        u16* fr = &fb[(iw * 32 + r) * 328 + cb];
                        float v0 = (o[iw][ct][4 * g + 0] * fsc[iw] + b2f(fr[0])) * inv[iw];
                        float v1 = (o[iw][ct][4 * g + 1] * fsc[iw] + b2f(fr[1])) * inv[iw];
                        float v2 = (o[iw][ct][4 * g + 2] * fsc[iw] + b2f(fr[2])) * inv[iw];
                        float v3 = (o[iw][ct][4 * g + 3] * fsc[iw] + b2f(fr[3])) * inv[iw];
                        *(unsigned*)(fr) = cvt_pk_bf16(v0, v1);
                        *(unsigned*)(fr + 2) = cvt_pk_bf16(v2, v3);
                    }
        }
        __syncthreads();    // syncC
        #undef PV_BODY
        #undef STAGE
    }

    // ---- common: store AO (64 q-rows x 320 ch) from smem [64][328] ----
    const u16* ob = (const u16*)smem;
    u16* AOb = AO + ((size_t)b * NN + i0) * CU;
    #pragma unroll
    for (int n = 0; n < 2; ++n) {
        int id = n * 896 + t;
        if (id < 2560) {
            int row = id / 40, c8 = id % 40;
            bf16x8 val = *(const bf16x8*)(ob + row * 328 + c8 * 8);
            *(bf16x8*)(AOb + (size_t)row * CU + c8 * 8) = val;
        }
    }
    if (t < 768) {
        int id = 1792 + t;
        int row = id / 40, c8 = id % 40;
        bf16x8 val = *(const bf16x8*)(ob + row * 328 + c8 * 8);
        *(bf16x8*)(AOb + (size_t)row * CU + c8 * 8) = val;
    }
}

extern "C" void kernel_launch(void* const* d_in, const int* in_sizes, int n_in,
                              void* d_out, int out_size, void* d_ws, size_t ws_size,
                              hipStream_t stream) {
    const float* unet  = (const float*)d_in[0];
    const float* janus = (const float*)d_in[1];
    const float* Wq = (const float*)d_in[2];
    const float* bq = (const float*)d_in[3];
    const float* Wk = (const float*)d_in[4];
    const float* bk = (const float*)d_in[5];
    const float* Wv = (const float*)d_in[6];
    const float* bv = (const float*)d_in[7];
    const float* Wo = (const float*)d_in[8];
    const float* bo = (const float*)d_in[9];
    float* out = (float*)d_out;

    char* ws = (char*)d_ws;
    u16* Xu  = (u16*)(ws + XU_OFF);
    u16* Xj  = (u16*)(ws + XJ_OFF);
    u16* Qb  = (u16*)(ws + QB_OFF);
    u16* Kb  = (u16*)(ws + KB_OFF);
    u16* Vb  = (u16*)(ws + VB_OFF);
    u16* wq  = (u16*)(ws + WQ_OFF);
    u16* wk  = (u16*)(ws + WK_OFF);
    u16* wv  = (u16*)(ws + WV_OFF);
    u16* wo  = (u16*)(ws + WO_OFF);
    u16* AO  = (u16*)(ws + AO_OFF);

    wcast_kernel<<<3024, 256, 0, stream>>>(Wq, Wk, Wv, Wo, wq, wk, wv, wo);

    transpose_cast_kernel<<<dim3(64, 5, NB), 256, 0, stream>>>(unet, Xu, CU, NN);
    transpose_cast_kernel<<<dim3(64, 16, NB), 256, 0, stream>>>(janus, Xj, CJ, NN);

    // Q pre-scaled by (1/16) * log2(e) so softmax runs in exp2 domain
    gemm_kernel<0, 320, 256><<<dim3(128, 4), 256, 0, stream>>>(
        Xu, wq, bq, Qb, nullptr, 0.0901684411f);

    // fused K + V projections (Xj staged once per tile, L2-shared)
    gemm_kv_kernel<<<dim3(128, 9), 256, 0, stream>>>(
        Xj, wk, wv, bk, bv, Kb, Vb);

    attn_kernel<<<256, 896, 0, stream>>>(Qb, Kb, Vb, AO);

    gemm_kernel<2, 320, 320><<<dim3(128, 5), 256, 0, stream>>>(
        AO, wo, bo, out, unet, 1.0f);
}

// Round 18
// 182.578 us; speedup vs baseline: 1.0068x; 1.0068x over previous
//
#include <hip/hip_runtime.h>
#include <hip/hip_bf16.h>
#include <math.h>

// ---------------------------------------------------------------------------
// CrossModalAttention on MI355X (gfx950)
//   B=4, Cu=320, Cj=1024, H=W=64 (N=4096), ATTN_DIM=256, scale = 1/16
// Round 18: attn reverted to R16 (best, 110us). GEMMs retiled 128x64 ->
// 256x64 with 512-thr blocks: per-wave footprint (64x32) and epilogues
// unchanged; LDS 2x40,960B -> 2 blocks/CU = 16 waves/CU (2x TLP).
// Prep (wcast + both transposes) fused into one kernel.
// ---------------------------------------------------------------------------

typedef unsigned short u16;
typedef __attribute__((ext_vector_type(8))) short bf16x8;
typedef __attribute__((ext_vector_type(4))) float f32x4;
typedef __attribute__((ext_vector_type(16))) float f32x16;
typedef __attribute__((ext_vector_type(4))) unsigned short u16x4;

#define NB 4
#define CU 320
#define CJ 1024
#define NN 4096
#define AD 256

// ws layout (bytes)
#define XU_OFF 0u
#define XJ_OFF 10485760u
#define QB_OFF 44040192u
#define KB_OFF 52428800u
#define VB_OFF 60817408u
#define WQ_OFF 71303168u
#define WK_OFF 71467008u
#define WV_OFF 71991296u
#define WO_OFF 72646656u
#define AO_OFF XU_OFF

__device__ __forceinline__ u16 f2b(float f) {
    union { float f; unsigned u; } v; v.f = f;
    unsigned u = v.u;
    unsigned r = (u + 0x7fffu + ((u >> 16) & 1u)) >> 16;
    return (u16)r;
}

__device__ __forceinline__ float b2f(u16 x) {
    union { unsigned u; float f; } v; v.u = ((unsigned)x) << 16;
    return v.f;
}

__device__ __forceinline__ unsigned cvt_pk_bf16(float lo, float hi) {
    unsigned r;
    asm("v_cvt_pk_bf16_f32 %0, %1, %2" : "=v"(r) : "v"(lo), "v"(hi));
    return r;
}

__device__ __forceinline__ float exp2_fast(float x) {
    float r;
    asm("v_exp_f32 %0, %1" : "=v"(r) : "v"(x));
    return r;
}

__device__ __forceinline__ void async_cp16(const u16* g, char* l) {
    __builtin_amdgcn_global_load_lds(
        (const __attribute__((address_space(1))) unsigned int*)g,
        (__attribute__((address_space(3))) unsigned int*)l, 16, 0, 0);
}

// ---------------- fused prep: transpose unet, transpose janus, weight cast ----
// grid 8400 x 256: [0,1280) unet transpose; [1280,5376) janus; [5376,8400) wcast
__global__ __launch_bounds__(256) void prep_kernel(
        const float* __restrict__ unet, const float* __restrict__ janus,
        const float* __restrict__ Wq, const float* __restrict__ Wk,
        const float* __restrict__ Wv, const float* __restrict__ Wo,
        u16* __restrict__ Xu, u16* __restrict__ Xj,
        u16* __restrict__ wq, u16* __restrict__ wk,
        u16* __restrict__ wv, u16* __restrict__ wo) {
    __shared__ float tile[64][65];
    int bid = blockIdx.x;
    int t = threadIdx.x;

    if (bid < 5376) {
        const float* src;
        u16* dst;
        int C, x, y, z;
        if (bid < 1280) {
            z = bid / 320; int rem = bid % 320; y = rem / 64; x = rem % 64;
            C = CU; src = unet + (size_t)z * CU * NN; dst = Xu + (size_t)z * NN * CU;
        } else {
            int idx = bid - 1280;
            z = idx / 1024; int rem = idx % 1024; y = rem / 64; x = rem % 64;
            C = CJ; src = janus + (size_t)z * CJ * NN; dst = Xj + (size_t)z * NN * CJ;
        }
        int n0 = x * 64, c0 = y * 64;
        int nl = t & 63, cl = t >> 6;
        #pragma unroll
        for (int k = 0; k < 16; ++k) {
            int c = cl + k * 4;
            tile[c][nl] = src[(size_t)(c0 + c) * NN + n0 + nl];
        }
        __syncthreads();
        int cl2 = t & 63, nl2 = t >> 6;
        #pragma unroll
        for (int k = 0; k < 16; ++k) {
            int n = nl2 + k * 4;
            dst[(size_t)(n0 + n) * C + c0 + cl2] = f2b(tile[cl2][n]);
        }
        return;
    }
    int id = (bid - 5376) * 256 + t;
    if (id < 81920) { wq[id] = f2b(Wq[id]); return; }
    id -= 81920;
    if (id < 262144) { wk[id] = f2b(Wk[id]); return; }
    id -= 262144;
    if (id < 327680) { wv[id] = f2b(Wv[id]); return; }
    id -= 327680;
    if (id < 102400) { wo[id] = f2b(Wo[id]); }
}

// ---------------- unified GEMM: out = A(16384xKD) @ W(NOUTxKD)^T ----------------
// 256x64 tile, BK=64, 8 waves (wr4 x wc2, 64x32 each), 2 blocks/CU.
// EPI 0: bf16 out [M][NOUT], val=(acc+bias)*alpha            (Q)
// EPI 2: f32  out [b][o][n] transposed + bias + unet res     (final)
template <int EPI, int KD, int NOUT>
__global__ __launch_bounds__(512, 4) void gemm_kernel(
        const u16* __restrict__ A, const u16* __restrict__ W,
        const float* __restrict__ bias, void* __restrict__ outp,
        const float* __restrict__ unet, float alpha) {
    __shared__ __align__(16) char smem[81920];
    const int t = threadIdx.x;
    const int lane = t & 63, wave = t >> 6;
    const int r = lane & 15, h = lane >> 4;
    const int wr = wave >> 1, wc = wave & 1;
    const int m0 = blockIdx.x * 256;
    const int bn0 = blockIdx.y * 64;

    int goffA[4], goffB;
    #pragma unroll
    for (int n = 0; n < 4; ++n) {
        int c = n * 512 + t;
        int row = c >> 3, s = c & 7;
        goffA[n] = (m0 + row) * KD + ((s ^ (row & 7)) << 3);
    }
    {
        int row = t >> 3, s = t & 7;
        goffB = (bn0 + row) * KD + ((s ^ (row & 7)) << 3);
    }
    const unsigned wb = (unsigned)(t & ~63) * 16u;

    #define GSTAGE(BUF, KT) do {                                                  \
        _Pragma("unroll")                                                         \
        for (int n_ = 0; n_ < 4; ++n_)                                            \
            async_cp16(A + goffA[n_] + (KT) * 64,                                 \
                       smem + (BUF) * 40960 + n_ * 8192 + wb);                    \
        async_cp16(W + goffB + (KT) * 64,                                         \
                   smem + (BUF) * 40960 + 32768 + wb);                            \
    } while (0)

    f32x4 acc[4][2];
    #pragma unroll
    for (int fr = 0; fr < 4; ++fr)
        #pragma unroll
        for (int fc = 0; fc < 2; ++fc) acc[fr][fc] = (f32x4)0.0f;

    GSTAGE(0, 0);
    int buf = 0;
    const int KS = KD / 64;
    for (int kt = 0; kt < KS; ++kt) {
        if (kt < KS - 1) {
            GSTAGE(buf ^ 1, kt + 1);
            asm volatile("s_waitcnt vmcnt(5)" ::: "memory");
        } else {
            asm volatile("s_waitcnt vmcnt(0)" ::: "memory");
        }
        __builtin_amdgcn_s_barrier();
        asm volatile("" ::: "memory");
        const char* Ab = smem + buf * 40960;
        const char* Bb = smem + buf * 40960 + 32768;
        #pragma unroll
        for (int kk = 0; kk < 2; ++kk) {
            bf16x8 af[4], bf[2];
            #pragma unroll
            for (int fr = 0; fr < 4; ++fr) {
                int row = wr * 64 + fr * 16 + r;
                af[fr] = *(const bf16x8*)(Ab + row * 128 + (((kk * 4 + h) ^ (row & 7)) << 4));
            }
            #pragma unroll
            for (int fc = 0; fc < 2; ++fc) {
                int rowb = wc * 32 + fc * 16 + r;
                bf[fc] = *(const bf16x8*)(Bb + rowb * 128 + (((kk * 4 + h) ^ (rowb & 7)) << 4));
            }
            #pragma unroll
            for (int fr = 0; fr < 4; ++fr)
                #pragma unroll
                for (int fc = 0; fc < 2; ++fc)
                    acc[fr][fc] = __builtin_amdgcn_mfma_f32_16x16x32_bf16(
                        af[fr], bf[fc], acc[fr][fc], 0, 0, 0);
        }
        asm volatile("" ::: "memory");
        __builtin_amdgcn_s_barrier();
        asm volatile("" ::: "memory");
        buf ^= 1;
    }
    #undef GSTAGE

    const int mw = m0 + wr * 64;
    const int ob0 = bn0 + wc * 32;

    if (EPI == 0) {
        u16* out = (u16*)outp;
        #pragma unroll
        for (int fc = 0; fc < 2; ++fc) {
            int o = ob0 + fc * 16 + r;
            float bs = bias[o];
            #pragma unroll
            for (int fr = 0; fr < 4; ++fr)
                #pragma unroll
                for (int rr = 0; rr < 4; ++rr) {
                    int mrow = mw + fr * 16 + h * 4 + rr;
                    out[(size_t)mrow * NOUT + o] = f2b((acc[fr][fc][rr] + bs) * alpha);
                }
        }
    } else {
        float* tile = (float*)(smem + wave * 8704);   // [32][68] f32
        #pragma unroll
        for (int fc = 0; fc < 2; ++fc)
            #pragma unroll
            for (int fr = 0; fr < 4; ++fr)
                *(f32x4*)(tile + (fc * 16 + r) * 68 + fr * 16 + h * 4) = acc[fr][fc];
        __builtin_amdgcn_s_waitcnt(0);
        float* out = (float*)outp;
        int bb = mw >> 12, nb = mw & 4095;
        #pragma unroll
        for (int g = 0; g < 8; ++g) {
            int chunk = g * 64 + lane;
            int row = chunk >> 4, ns = chunk & 15;
            int o = ob0 + row;
            size_t base = (size_t)bb * CU * NN + (size_t)o * NN + nb + ns * 4;
            f32x4 v = *(const f32x4*)(tile + row * 68 + ns * 4);
            f32x4 u = *(const f32x4*)(unet + base);
            float bs = bias[o];
            f32x4 res;
            #pragma unroll
            for (int rr = 0; rr < 4; ++rr) res[rr] = v[rr] + bs + u[rr];
            *(f32x4*)(out + base) = res;
        }
    }
}

// ---------------- fused K+V projection (KD=1024, 256x64 tile) ----------------
// grid (64, 9): y<4 -> K (bf16 [M][256]); y>=4 -> V (fragment order V').
__global__ __launch_bounds__(512, 4) void gemm_kv_kernel(
        const u16* __restrict__ A, const u16* __restrict__ Wk,
        const u16* __restrict__ Wv, const float* __restrict__ bk,
        const float* __restrict__ bv, u16* __restrict__ Kb,
        u16* __restrict__ Vb) {
    const int KD = 1024;
    __shared__ __align__(16) char smem[81920];
    const int t = threadIdx.x;
    const int lane = t & 63, wave = t >> 6;
    const int r = lane & 15, h = lane >> 4;
    const int wr = wave >> 1, wc = wave & 1;
    const int m0 = blockIdx.x * 256;
    const bool isK = blockIdx.y < 4;
    const int bn0 = (isK ? blockIdx.y : (blockIdx.y - 4)) * 64;
    const u16* W = isK ? Wk : Wv;
    const float* bias = isK ? bk : bv;

    int goffA[4], goffB;
    #pragma unroll
    for (int n = 0; n < 4; ++n) {
        int c = n * 512 + t;
        int row = c >> 3, s = c & 7;
        goffA[n] = (m0 + row) * KD + ((s ^ (row & 7)) << 3);
    }
    {
        int row = t >> 3, s = t & 7;
        goffB = (bn0 + row) * KD + ((s ^ (row & 7)) << 3);
    }
    const unsigned wb = (unsigned)(t & ~63) * 16u;

    #define GSTAGE(BUF, KT) do {                                                  \
        _Pragma("unroll")                                                         \
        for (int n_ = 0; n_ < 4; ++n_)                                            \
            async_cp16(A + goffA[n_] + (KT) * 64,                                 \
                       smem + (BUF) * 40960 + n_ * 8192 + wb);                    \
        async_cp16(W + goffB + (KT) * 64,                                         \
                   smem + (BUF) * 40960 + 32768 + wb);                            \
    } while (0)

    f32x4 acc[4][2];
    #pragma unroll
    for (int fr = 0; fr < 4; ++fr)
        #pragma unroll
        for (int fc = 0; fc < 2; ++fc) acc[fr][fc] = (f32x4)0.0f;

    GSTAGE(0, 0);
    int buf = 0;
    for (int kt = 0; kt < 16; ++kt) {
        if (kt < 15) {
            GSTAGE(buf ^ 1, kt + 1);
            asm volatile("s_waitcnt vmcnt(5)" ::: "memory");
        } else {
            asm volatile("s_waitcnt vmcnt(0)" ::: "memory");
        }
        __builtin_amdgcn_s_barrier();
        asm volatile("" ::: "memory");
        const char* Ab = smem + buf * 40960;
        const char* Bb = smem + buf * 40960 + 32768;
        #pragma unroll
        for (int kk = 0; kk < 2; ++kk) {
            bf16x8 af[4], bf[2];
            #pragma unroll
            for (int fr = 0; fr < 4; ++fr) {
                int row = wr * 64 + fr * 16 + r;
                af[fr] = *(const bf16x8*)(Ab + row * 128 + (((kk * 4 + h) ^ (row & 7)) << 4));
            }
            #pragma unroll
            for (int fc = 0; fc < 2; ++fc) {
                int rowb = wc * 32 + fc * 16 + r;
                bf[fc] = *(const bf16x8*)(Bb + rowb * 128 + (((kk * 4 + h) ^ (rowb & 7)) << 4));
            }
            #pragma unroll
            for (int fr = 0; fr < 4; ++fr)
                #pragma unroll
                for (int fc = 0; fc < 2; ++fc)
                    acc[fr][fc] = __builtin_amdgcn_mfma_f32_16x16x32_bf16(
                        af[fr], bf[fc], acc[fr][fc], 0, 0, 0);
        }
        asm volatile("" ::: "memory");
        __builtin_amdgcn_s_barrier();
        asm volatile("" ::: "memory");
        buf ^= 1;
    }
    #undef GSTAGE

    const int mw = m0 + wr * 64;
    const int ob0 = bn0 + wc * 32;

    if (isK) {
        #pragma unroll
        for (int fc = 0; fc < 2; ++fc) {
            int o = ob0 + fc * 16 + r;
            float bs = bias[o];
            #pragma unroll
            for (int fr = 0; fr < 4; ++fr)
                #pragma unroll
                for (int rr = 0; rr < 4; ++rr) {
                    int mrow = mw + fr * 16 + h * 4 + rr;
                    Kb[(size_t)mrow * AD + o] = f2b((acc[fr][fc][rr] + bs));
                }
        }
    } else {
        u16* tile = (u16*)(smem + wave * 4608);
        #pragma unroll
        for (int fc = 0; fc < 2; ++fc) {
            int o = ob0 + fc * 16 + r;
            float bs = bias[o];
            #pragma unroll
            for (int fr = 0; fr < 4; ++fr) {
                u16x4 v4;
                #pragma unroll
                for (int rr = 0; rr < 4; ++rr) v4[rr] = f2b(acc[fr][fc][rr] + bs);
                *(u16x4*)(tile + (fc * 16 + r) * 72 + fr * 16 + h * 4) = v4;
            }
        }
        __builtin_amdgcn_s_waitcnt(0);
        int bb = mw >> 12, nb = mw & 4095;
        #pragma unroll
        for (int g = 0; g < 4; ++g) {
            int chunk = g * 64 + lane;
            int row = chunk >> 3, ns = chunk & 7;
            int ch = ob0 + row;
            int j = nb + ns * 8;
            bf16x8 val = *(const bf16x8*)(tile + row * 72 + ns * 8);
            size_t off = (size_t)bb * CU * NN + (size_t)(ch >> 5) * (NN * 32)
                       + (size_t)(j >> 4) * 512
                       + (size_t)((ch & 31) + ((j >> 3) & 1) * 32) * 8 + (j & 7);
            *(bf16x8*)(Vb + off) = val;
        }
    }
}

// ---------------- flash attention (R16, proven 110us) -----------------------
// 256 blocks x 768 thr (12 waves): waves 0-3 = QK (iw = w>>1, jw = w&1),
// waves 4-11 = PV (iw = pvid>>2, pj = (pvid>>1)&1, cgh = pvid&1, o[5]).
__global__ __launch_bounds__(768, 3) void attn_kernel(
        const u16* __restrict__ Q, const u16* __restrict__ K,
        const u16* __restrict__ V, u16* __restrict__ AO) {
    __shared__ __align__(16) char smem[84480];

    const int t = threadIdx.x;
    const int lane = t & 63;
    const int wave = t >> 6;          // 0..11
    const int r = lane & 31, hi = lane >> 5;

    int linear = blockIdx.x;
    int swz = (linear & 7) * 32 + (linear >> 3);
    int b = swz >> 6;
    int i0 = (swz & 63) * 64;

    const u16* Qb = Q + ((size_t)b * NN + i0) * AD;
    const u16* Kb = K + (size_t)b * NN * AD;
    const u16* Vb = V + (size_t)b * CU * NN;

    // ---- prologue: stage K[0] (2048 chunks) with all 768 threads ----
    {
        #pragma unroll
        for (int n = 0; n < 2; ++n) {
            int id = n * 768 + t;
            int row = (id >> 5) & 63, c16 = id & 31;
            async_cp16(Kb + row * 256 + ((c16 ^ (row & 31)) << 3),
                       smem + (unsigned)(n * 768 + (t & ~63)) * 16u);
        }
        if (t < 512) {
            int id = 1536 + t;
            int row = (id >> 5) & 63, c16 = id & 31;
            async_cp16(Kb + row * 256 + ((c16 ^ (row & 31)) << 3),
                       smem + (unsigned)(1536 + (t & ~63)) * 16u);
        }
    }
    asm volatile("s_waitcnt vmcnt(0)" ::: "memory");
    __builtin_amdgcn_s_barrier();     // K[0] ready
    asm volatile("" ::: "memory");

    if (wave < 4) {
        // ================= QK role =================
        const int iw = wave >> 1;
        const int jw = wave & 1;
        bf16x8 q[16];
        #pragma unroll
        for (int kk = 0; kk < 16; ++kk)
            q[kk] = *(const bf16x8*)(Qb + (size_t)(iw * 32 + r) * AD + kk * 16 + hi * 8);
        float m = -INFINITY, lsum = 0.0f;

        for (int i = 0; i < 64; ++i) {
            if (i) {
                __builtin_amdgcn_s_barrier();
                asm volatile("" ::: "memory");
            }
            const char* Kt = smem + (i & 1) * 32768 + jw * 16384;
            f32x16 sa = (f32x16)0.0f, sb = (f32x16)0.0f;
            __builtin_amdgcn_s_setprio(1);
            #pragma unroll
            for (int kk = 0; kk < 8; ++kk) {
                bf16x8 k0 = *(const bf16x8*)(Kt + r * 512 + (((2 * kk + hi) ^ r) << 4));
                bf16x8 k1 = *(const bf16x8*)(Kt + r * 512 + (((2 * (kk + 8) + hi) ^ r) << 4));
                sa = __builtin_amdgcn_mfma_f32_32x32x16_bf16(k0, q[kk], sa, 0, 0, 0);
                sb = __builtin_amdgcn_mfma_f32_32x32x16_bf16(k1, q[kk + 8], sb, 0, 0, 0);
            }
            __builtin_amdgcn_s_setprio(0);
            f32x16 s = sa + sb;

            float x0 = fmaxf(s[0], s[1]),   x1 = fmaxf(s[2], s[3]);
            float x2 = fmaxf(s[4], s[5]),   x3 = fmaxf(s[6], s[7]);
            float x4 = fmaxf(s[8], s[9]),   x5 = fmaxf(s[10], s[11]);
            float x6 = fmaxf(s[12], s[13]), x7 = fmaxf(s[14], s[15]);
            float pmax = fmaxf(fmaxf(fmaxf(x0, x1), fmaxf(x2, x3)),
                               fmaxf(fmaxf(x4, x5), fmaxf(x6, x7)));
            pmax = fmaxf(pmax, __shfl_xor(pmax, 32));
            char* pb = smem + 65536 + (i & 1) * 8960;
            int fl = __any(pmax > m + 8.0f) ? 1 : 0;
            if (fl) {
                float mn = fmaxf(m, pmax);
                float al = exp2_fast(m - mn);
                m = mn;
                lsum *= al;
                if (lane < 32) *(float*)(pb + 8192 + (iw * 2 + jw) * 128 + r * 4) = al;
            }
            if (lane == 0) *(int*)(pb + 8704 + (iw * 2 + jw) * 4) = fl;
            float p[16];
            #pragma unroll
            for (int e = 0; e < 16; ++e) p[e] = exp2_fast(s[e] - m);
            float y0 = (p[0] + p[1]) + (p[2] + p[3]);
            float y1 = (p[4] + p[5]) + (p[6] + p[7]);
            float y2 = (p[8] + p[9]) + (p[10] + p[11]);
            float y3 = (p[12] + p[13]) + (p[14] + p[15]);
            float ps = (y0 + y1) + (y2 + y3);
            ps += __shfl_xor(ps, 32);
            lsum += ps;

            #pragma unroll
            for (int ks = 0; ks < 2; ++ks) {
                unsigned a0 = cvt_pk_bf16(p[8 * ks + 0], p[8 * ks + 1]);
                unsigned a1 = cvt_pk_bf16(p[8 * ks + 2], p[8 * ks + 3]);
                unsigned b0 = cvt_pk_bf16(p[8 * ks + 4], p[8 * ks + 5]);
                unsigned b1 = cvt_pk_bf16(p[8 * ks + 6], p[8 * ks + 7]);
                asm("v_permlane32_swap_b32 %0, %1" : "+v"(a0), "+v"(b0));
                asm("v_permlane32_swap_b32 %0, %1" : "+v"(a1), "+v"(b1));
                union { unsigned w[4]; bf16x8 v; } u;
                u.w[0] = a0; u.w[1] = a1; u.w[2] = b0; u.w[3] = b1;
                *(bf16x8*)(pb + (iw * 2 + jw) * 2048 + ks * 1024 + lane * 16) = u.v;
            }
            asm volatile("s_waitcnt lgkmcnt(0)" ::: "memory");
            __builtin_amdgcn_sched_barrier(0);
        }
        __builtin_amdgcn_s_barrier();   // P(63) published
        asm volatile("" ::: "memory");
        if (lane < 32) {
            *(float*)(smem + 83456 + (iw * 2 + jw) * 128 + r * 4) = m;
            *(float*)(smem + 83456 + 512 + (iw * 2 + jw) * 128 + r * 4) = lsum;
        }
        __syncthreads();    // syncA
        __syncthreads();    // syncB
        __syncthreads();    // syncC
    } else {
        // ================= PV role =================
        const int pvid = wave - 4;          // 0..7
        const int iw = pvid >> 2;           // 32-row group
        const int pj = (pvid >> 1) & 1;     // which jw's P
        const int cgh = pvid & 1;           // 160-ch half
        const int tp = t - 256;             // 0..511 over waves 4-11

        int goffp[4];
        #pragma unroll
        for (int n = 0; n < 4; ++n) {
            int id = n * 512 + tp;
            int row = (id >> 5) & 63;
            int c16 = id & 31;
            goffp[n] = row * 256 + ((c16 ^ (row & 31)) << 3);
        }
        const unsigned wbp = (unsigned)(tp & ~63) * 16u;

        #define STAGE(BUF, KP) do {                                               \
            _Pragma("unroll")                                                     \
            for (int n_ = 0; n_ < 4; ++n_)                                        \
                async_cp16((KP) + goffp[n_],                                      \
                           smem + (BUF) * 32768 + n_ * 8192 + wbp);               \
        } while (0)

        f32x16 o[5];
        #pragma unroll
        for (int ct = 0; ct < 5; ++ct) o[ct] = (f32x16)0.0f;
        const u16* vb = Vb + (size_t)(cgh * 5) * 131072 + lane * 8;

        #define PV_BODY(TI) do {                                                  \
            const char* pb = smem + 65536 + ((TI) & 1) * 8960;                    \
            int fl = *(volatile const int*)(pb + 8704 + (iw * 2 + pj) * 4);       \
            bf16x8 pf0 = *(const bf16x8*)(pb + (iw * 2 + pj) * 2048 + lane * 16); \
            bf16x8 pf1 = *(const bf16x8*)(pb + (iw * 2 + pj) * 2048 + 1024 +      \
                                          lane * 16);                             \
            bf16x8 vfA[5], vfB[5];                                                \
            _Pragma("unroll")                                                     \
            for (int c = 0; c < 5; ++c)                                           \
                vfA[c] = *(const bf16x8*)(vb + (size_t)c * 131072 +               \
                                          ((TI) * 4 + pj * 2 + 0) * 512);         \
            _Pragma("unroll")                                                     \
            for (int c = 0; c < 5; ++c)                                           \
                vfB[c] = *(const bf16x8*)(vb + (size_t)c * 131072 +               \
                                          ((TI) * 4 + pj * 2 + 1) * 512);         \
            if (fl) {                                                             \
                float alv = *(volatile const float*)(pb + 8192 +                  \
                                (iw * 2 + pj) * 128 + (lane & 31) * 4);           \
                _Pragma("unroll")                                                 \
                for (int ct = 0; ct < 5; ++ct) o[ct] *= alv;                      \
            }                                                                     \
            __builtin_amdgcn_s_setprio(1);                                        \
            _Pragma("unroll")                                                     \
            for (int ct = 0; ct < 5; ++ct)                                        \
                o[ct] = __builtin_amdgcn_mfma_f32_32x32x16_bf16(vfA[ct], pf0,     \
                                                                o[ct], 0, 0, 0); \
            _Pragma("unroll")                                                     \
            for (int ct = 0; ct < 5; ++ct)                                        \
                o[ct] = __builtin_amdgcn_mfma_f32_32x32x16_bf16(vfB[ct], pf1,     \
                                                                o[ct], 0, 0, 0); \
            __builtin_amdgcn_s_setprio(0);                                        \
        } while (0)

        for (int i = 0; i < 64; ++i) {
            if (i) {
                __builtin_amdgcn_s_barrier();
                asm volatile("" ::: "memory");
            }
            if (i < 63) STAGE((i + 1) & 1, Kb + (i + 1) * 16384);
            if (i >= 1) PV_BODY(i - 1);
            asm volatile("s_waitcnt vmcnt(0)" ::: "memory");
        }
        __builtin_amdgcn_s_barrier();   // P(63) published
        asm volatile("" ::: "memory");
        PV_BODY(63);

        __syncthreads();    // syncA: m/l published, kbuf dead
        float m0 = *(const float*)(smem + 83456 + (iw * 2 + pj) * 128 + r * 4);
        float l0 = *(const float*)(smem + 83456 + 512 + (iw * 2 + pj) * 128 + r * 4);
        float m1 = *(const float*)(smem + 83456 + (iw * 2 + (pj ^ 1)) * 128 + r * 4);
        float l1 = *(const float*)(smem + 83456 + 512 + (iw * 2 + (pj ^ 1)) * 128 + r * 4);
        float M = fmaxf(m0, m1);
        float fsc = exp2_fast(m0 - M);
        float fo = exp2_fast(m1 - M);
        float inv = 1.0f / (l0 * fsc + l1 * fo);

        u16* fb = (u16*)smem;              // [64][328] bf16, in-place merge
        if (pj == 1) {
            #pragma unroll
            for (int ct = 0; ct < 5; ++ct)
                #pragma unroll
                for (int e = 0; e < 16; ++e) {
                    int c = cgh * 160 + ct * 32 + (e & 3) + 8 * (e >> 2) + 4 * hi;
                    fb[(iw * 32 + r) * 328 + c] = f2b(o[ct][e] * fsc);
                }
        }
        __syncthreads();    // syncB
        if (pj == 0) {
            #pragma unroll
            for (int ct = 0; ct < 5; ++ct)
                #pragma unroll
                for (int g = 0; g < 4; ++g) {
                    int cb = cgh * 160 + ct * 32 + 8 * g + 4 * hi;
                    u16* fr = &fb[(iw * 32 + r) * 328 + cb];
                    float v0 = (o[ct][4 * g + 0] * fsc + b2f(fr[0])) * inv;
                    float v1 = (o[ct][4 * g + 1] * fsc + b2f(fr[1])) * inv;
                    float v2 = (o[ct][4 * g + 2] * fsc + b2f(fr[2])) * inv;
                    float v3 = (o[ct][4 * g + 3] * fsc + b2f(fr[3])) * inv;
                    *(unsigned*)(fr) = cvt_pk_bf16(v0, v1);
                    *(unsigned*)(fr + 2) = cvt_pk_bf16(v2, v3);
                }
        }
        __syncthreads();    // syncC
        #undef PV_BODY
        #undef STAGE
    }

    // ---- common: store AO (64 q-rows x 320 ch) from smem [64][328] ----
    const u16* ob = (const u16*)smem;
    u16* AOb = AO + ((size_t)b * NN + i0) * CU;
    #pragma unroll
    for (int n = 0; n < 3; ++n) {
        int id = n * 768 + t;
        int row = id / 40, c8 = id % 40;
        bf16x8 val = *(const bf16x8*)(ob + row * 328 + c8 * 8);
        *(bf16x8*)(AOb + (size_t)row * CU + c8 * 8) = val;
    }
    if (t < 256) {
        int id = 2304 + t;
        int row = id / 40, c8 = id % 40;
        bf16x8 val = *(const bf16x8*)(ob + row * 328 + c8 * 8);
        *(bf16x8*)(AOb + (size_t)row * CU + c8 * 8) = val;
    }
}

extern "C" void kernel_launch(void* const* d_in, const int* in_sizes, int n_in,
                              void* d_out, int out_size, void* d_ws, size_t ws_size,
                              hipStream_t stream) {
    const float* unet  = (const float*)d_in[0];
    const float* janus = (const float*)d_in[1];
    const float* Wq = (const float*)d_in[2];
    const float* bq = (const float*)d_in[3];
    const float* Wk = (const float*)d_in[4];
    const float* bk = (const float*)d_in[5];
    const float* Wv = (const float*)d_in[6];
    const float* bv = (const float*)d_in[7];
    const float* Wo = (const float*)d_in[8];
    const float* bo = (const float*)d_in[9];
    float* out = (float*)d_out;

    char* ws = (char*)d_ws;
    u16* Xu  = (u16*)(ws + XU_OFF);
    u16* Xj  = (u16*)(ws + XJ_OFF);
    u16* Qb  = (u16*)(ws + QB_OFF);
    u16* Kb  = (u16*)(ws + KB_OFF);
    u16* Vb  = (u16*)(ws + VB_OFF);
    u16* wq  = (u16*)(ws + WQ_OFF);
    u16* wk  = (u16*)(ws + WK_OFF);
    u16* wv  = (u16*)(ws + WV_OFF);
    u16* wo  = (u16*)(ws + WO_OFF);
    u16* AO  = (u16*)(ws + AO_OFF);

    // fused prep: transposes + weight cast
    prep_kernel<<<8400, 256, 0, stream>>>(unet, janus, Wq, Wk, Wv, Wo,
                                          Xu, Xj, wq, wk, wv, wo);

    // Q pre-scaled by (1/16) * log2(e) so softmax runs in exp2 domain
    gemm_kernel<0, 320, 256><<<dim3(64, 4), 512, 0, stream>>>(
        Xu, wq, bq, Qb, nullptr, 0.0901684411f);

    // fused K + V projections
    gemm_kv_kernel<<<dim3(64, 9), 512, 0, stream>>>(
        Xj, wk, wv, bk, bv, Kb, Vb);

    attn_kernel<<<256, 768, 0, stream>>>(Qb, Kb, Vb, AO);

    gemm_kernel<2, 320, 320><<<dim3(64, 5), 512, 0, stream>>>(
        AO, wo, bo, out, unet, 1.0f);
}

// Round 19
// 172.713 us; speedup vs baseline: 1.0643x; 1.0571x over previous
//
#include <hip/hip_runtime.h>
#include <hip/hip_bf16.h>
#include <math.h>

// ---------------------------------------------------------------------------
// CrossModalAttention on MI355X (gfx950)
//   B=4, Cu=320, Cj=1024, H=W=64 (N=4096), ATTN_DIM=256, scale = 1/16
// Round 19: attn K-staging made 3-deep (kbuf x3). PV body: PV_BODY first,
// STAGE K[i+2] last -> stage loads are newest VM ops, V-use waits never
// drain them; each stage gets a full iteration of latency cover (vs ~500cyc
// in R16's 2-deep). Everything else identical to R18.
// ---------------------------------------------------------------------------

typedef unsigned short u16;
typedef __attribute__((ext_vector_type(8))) short bf16x8;
typedef __attribute__((ext_vector_type(4))) float f32x4;
typedef __attribute__((ext_vector_type(16))) float f32x16;
typedef __attribute__((ext_vector_type(4))) unsigned short u16x4;

#define NB 4
#define CU 320
#define CJ 1024
#define NN 4096
#define AD 256

// ws layout (bytes)
#define XU_OFF 0u
#define XJ_OFF 10485760u
#define QB_OFF 44040192u
#define KB_OFF 52428800u
#define VB_OFF 60817408u
#define WQ_OFF 71303168u
#define WK_OFF 71467008u
#define WV_OFF 71991296u
#define WO_OFF 72646656u
#define AO_OFF XU_OFF

__device__ __forceinline__ u16 f2b(float f) {
    union { float f; unsigned u; } v; v.f = f;
    unsigned u = v.u;
    unsigned r = (u + 0x7fffu + ((u >> 16) & 1u)) >> 16;
    return (u16)r;
}

__device__ __forceinline__ float b2f(u16 x) {
    union { unsigned u; float f; } v; v.u = ((unsigned)x) << 16;
    return v.f;
}

__device__ __forceinline__ unsigned cvt_pk_bf16(float lo, float hi) {
    unsigned r;
    asm("v_cvt_pk_bf16_f32 %0, %1, %2" : "=v"(r) : "v"(lo), "v"(hi));
    return r;
}

__device__ __forceinline__ float exp2_fast(float x) {
    float r;
    asm("v_exp_f32 %0, %1" : "=v"(r) : "v"(x));
    return r;
}

__device__ __forceinline__ void async_cp16(const u16* g, char* l) {
    __builtin_amdgcn_global_load_lds(
        (const __attribute__((address_space(1))) unsigned int*)g,
        (__attribute__((address_space(3))) unsigned int*)l, 16, 0, 0);
}

// ---------------- fused prep: transpose unet, transpose janus, weight cast ----
__global__ __launch_bounds__(256) void prep_kernel(
        const float* __restrict__ unet, const float* __restrict__ janus,
        const float* __restrict__ Wq, const float* __restrict__ Wk,
        const float* __restrict__ Wv, const float* __restrict__ Wo,
        u16* __restrict__ Xu, u16* __restrict__ Xj,
        u16* __restrict__ wq, u16* __restrict__ wk,
        u16* __restrict__ wv, u16* __restrict__ wo) {
    __shared__ float tile[64][65];
    int bid = blockIdx.x;
    int t = threadIdx.x;

    if (bid < 5376) {
        const float* src;
        u16* dst;
        int C, x, y, z;
        if (bid < 1280) {
            z = bid / 320; int rem = bid % 320; y = rem / 64; x = rem % 64;
            C = CU; src = unet + (size_t)z * CU * NN; dst = Xu + (size_t)z * NN * CU;
        } else {
            int idx = bid - 1280;
            z = idx / 1024; int rem = idx % 1024; y = rem / 64; x = rem % 64;
            C = CJ; src = janus + (size_t)z * CJ * NN; dst = Xj + (size_t)z * NN * CJ;
        }
        int n0 = x * 64, c0 = y * 64;
        int nl = t & 63, cl = t >> 6;
        #pragma unroll
        for (int k = 0; k < 16; ++k) {
            int c = cl + k * 4;
            tile[c][nl] = src[(size_t)(c0 + c) * NN + n0 + nl];
        }
        __syncthreads();
        int cl2 = t & 63, nl2 = t >> 6;
        #pragma unroll
        for (int k = 0; k < 16; ++k) {
            int n = nl2 + k * 4;
            dst[(size_t)(n0 + n) * C + c0 + cl2] = f2b(tile[cl2][n]);
        }
        return;
    }
    int id = (bid - 5376) * 256 + t;
    if (id < 81920) { wq[id] = f2b(Wq[id]); return; }
    id -= 81920;
    if (id < 262144) { wk[id] = f2b(Wk[id]); return; }
    id -= 262144;
    if (id < 327680) { wv[id] = f2b(Wv[id]); return; }
    id -= 327680;
    if (id < 102400) { wo[id] = f2b(Wo[id]); }
}

// ---------------- unified GEMM: out = A(16384xKD) @ W(NOUTxKD)^T ----------------
// 256x64 tile, BK=64, 8 waves (wr4 x wc2, 64x32 each), 2 blocks/CU.
template <int EPI, int KD, int NOUT>
__global__ __launch_bounds__(512, 4) void gemm_kernel(
        const u16* __restrict__ A, const u16* __restrict__ W,
        const float* __restrict__ bias, void* __restrict__ outp,
        const float* __restrict__ unet, float alpha) {
    __shared__ __align__(16) char smem[81920];
    const int t = threadIdx.x;
    const int lane = t & 63, wave = t >> 6;
    const int r = lane & 15, h = lane >> 4;
    const int wr = wave >> 1, wc = wave & 1;
    const int m0 = blockIdx.x * 256;
    const int bn0 = blockIdx.y * 64;

    int goffA[4], goffB;
    #pragma unroll
    for (int n = 0; n < 4; ++n) {
        int c = n * 512 + t;
        int row = c >> 3, s = c & 7;
        goffA[n] = (m0 + row) * KD + ((s ^ (row & 7)) << 3);
    }
    {
        int row = t >> 3, s = t & 7;
        goffB = (bn0 + row) * KD + ((s ^ (row & 7)) << 3);
    }
    const unsigned wb = (unsigned)(t & ~63) * 16u;

    #define GSTAGE(BUF, KT) do {                                                  \
        _Pragma("unroll")                                                         \
        for (int n_ = 0; n_ < 4; ++n_)                                            \
            async_cp16(A + goffA[n_] + (KT) * 64,                                 \
                       smem + (BUF) * 40960 + n_ * 8192 + wb);                    \
        async_cp16(W + goffB + (KT) * 64,                                         \
                   smem + (BUF) * 40960 + 32768 + wb);                            \
    } while (0)

    f32x4 acc[4][2];
    #pragma unroll
    for (int fr = 0; fr < 4; ++fr)
        #pragma unroll
        for (int fc = 0; fc < 2; ++fc) acc[fr][fc] = (f32x4)0.0f;

    GSTAGE(0, 0);
    int buf = 0;
    const int KS = KD / 64;
    for (int kt = 0; kt < KS; ++kt) {
        if (kt < KS - 1) {
            GSTAGE(buf ^ 1, kt + 1);
            asm volatile("s_waitcnt vmcnt(5)" ::: "memory");
        } else {
            asm volatile("s_waitcnt vmcnt(0)" ::: "memory");
        }
        __builtin_amdgcn_s_barrier();
        asm volatile("" ::: "memory");
        const char* Ab = smem + buf * 40960;
        const char* Bb = smem + buf * 40960 + 32768;
        #pragma unroll
        for (int kk = 0; kk < 2; ++kk) {
            bf16x8 af[4], bf[2];
            #pragma unroll
            for (int fr = 0; fr < 4; ++fr) {
                int row = wr * 64 + fr * 16 + r;
                af[fr] = *(const bf16x8*)(Ab + row * 128 + (((kk * 4 + h) ^ (row & 7)) << 4));
            }
            #pragma unroll
            for (int fc = 0; fc < 2; ++fc) {
                int rowb = wc * 32 + fc * 16 + r;
                bf[fc] = *(const bf16x8*)(Bb + rowb * 128 + (((kk * 4 + h) ^ (rowb & 7)) << 4));
            }
            #pragma unroll
            for (int fr = 0; fr < 4; ++fr)
                #pragma unroll
                for (int fc = 0; fc < 2; ++fc)
                    acc[fr][fc] = __builtin_amdgcn_mfma_f32_16x16x32_bf16(
                        af[fr], bf[fc], acc[fr][fc], 0, 0, 0);
        }
        asm volatile("" ::: "memory");
        __builtin_amdgcn_s_barrier();
        asm volatile("" ::: "memory");
        buf ^= 1;
    }
    #undef GSTAGE

    const int mw = m0 + wr * 64;
    const int ob0 = bn0 + wc * 32;

    if (EPI == 0) {
        u16* out = (u16*)outp;
        #pragma unroll
        for (int fc = 0; fc < 2; ++fc) {
            int o = ob0 + fc * 16 + r;
            float bs = bias[o];
            #pragma unroll
            for (int fr = 0; fr < 4; ++fr)
                #pragma unroll
                for (int rr = 0; rr < 4; ++rr) {
                    int mrow = mw + fr * 16 + h * 4 + rr;
                    out[(size_t)mrow * NOUT + o] = f2b((acc[fr][fc][rr] + bs) * alpha);
                }
        }
    } else {
        float* tile = (float*)(smem + wave * 8704);   // [32][68] f32
        #pragma unroll
        for (int fc = 0; fc < 2; ++fc)
            #pragma unroll
            for (int fr = 0; fr < 4; ++fr)
                *(f32x4*)(tile + (fc * 16 + r) * 68 + fr * 16 + h * 4) = acc[fr][fc];
        __builtin_amdgcn_s_waitcnt(0);
        float* out = (float*)outp;
        int bb = mw >> 12, nb = mw & 4095;
        #pragma unroll
        for (int g = 0; g < 8; ++g) {
            int chunk = g * 64 + lane;
            int row = chunk >> 4, ns = chunk & 15;
            int o = ob0 + row;
            size_t base = (size_t)bb * CU * NN + (size_t)o * NN + nb + ns * 4;
            f32x4 v = *(const f32x4*)(tile + row * 68 + ns * 4);
            f32x4 u = *(const f32x4*)(unet + base);
            float bs = bias[o];
            f32x4 res;
            #pragma unroll
            for (int rr = 0; rr < 4; ++rr) res[rr] = v[rr] + bs + u[rr];
            *(f32x4*)(out + base) = res;
        }
    }
}

// ---------------- fused K+V projection (KD=1024, 256x64 tile) ----------------
__global__ __launch_bounds__(512, 4) void gemm_kv_kernel(
        const u16* __restrict__ A, const u16* __restrict__ Wk,
        const u16* __restrict__ Wv, const float* __restrict__ bk,
        const float* __restrict__ bv, u16* __restrict__ Kb,
        u16* __restrict__ Vb) {
    const int KD = 1024;
    __shared__ __align__(16) char smem[81920];
    const int t = threadIdx.x;
    const int lane = t & 63, wave = t >> 6;
    const int r = lane & 15, h = lane >> 4;
    const int wr = wave >> 1, wc = wave & 1;
    const int m0 = blockIdx.x * 256;
    const bool isK = blockIdx.y < 4;
    const int bn0 = (isK ? blockIdx.y : (blockIdx.y - 4)) * 64;
    const u16* W = isK ? Wk : Wv;
    const float* bias = isK ? bk : bv;

    int goffA[4], goffB;
    #pragma unroll
    for (int n = 0; n < 4; ++n) {
        int c = n * 512 + t;
        int row = c >> 3, s = c & 7;
        goffA[n] = (m0 + row) * KD + ((s ^ (row & 7)) << 3);
    }
    {
        int row = t >> 3, s = t & 7;
        goffB = (bn0 + row) * KD + ((s ^ (row & 7)) << 3);
    }
    const unsigned wb = (unsigned)(t & ~63) * 16u;

    #define GSTAGE(BUF, KT) do {                                                  \
        _Pragma("unroll")                                                         \
        for (int n_ = 0; n_ < 4; ++n_)                                            \
            async_cp16(A + goffA[n_] + (KT) * 64,                                 \
                       smem + (BUF) * 40960 + n_ * 8192 + wb);                    \
        async_cp16(W + goffB + (KT) * 64,                                         \
                   smem + (BUF) * 40960 + 32768 + wb);                            \
    } while (0)

    f32x4 acc[4][2];
    #pragma unroll
    for (int fr = 0; fr < 4; ++fr)
        #pragma unroll
        for (int fc = 0; fc < 2; ++fc) acc[fr][fc] = (f32x4)0.0f;

    GSTAGE(0, 0);
    int buf = 0;
    for (int kt = 0; kt < 16; ++kt) {
        if (kt < 15) {
            GSTAGE(buf ^ 1, kt + 1);
            asm volatile("s_waitcnt vmcnt(5)" ::: "memory");
        } else {
            asm volatile("s_waitcnt vmcnt(0)" ::: "memory");
        }
        __builtin_amdgcn_s_barrier();
        asm volatile("" ::: "memory");
        const char* Ab = smem + buf * 40960;
        const char* Bb = smem + buf * 40960 + 32768;
        #pragma unroll
        for (int kk = 0; kk < 2; ++kk) {
            bf16x8 af[4], bf[2];
            #pragma unroll
            for (int fr = 0; fr < 4; ++fr) {
                int row = wr * 64 + fr * 16 + r;
                af[fr] = *(const bf16x8*)(Ab + row * 128 + (((kk * 4 + h) ^ (row & 7)) << 4));
            }
            #pragma unroll
            for (int fc = 0; fc < 2; ++fc) {
                int rowb = wc * 32 + fc * 16 + r;
                bf[fc] = *(const bf16x8*)(Bb + rowb * 128 + (((kk * 4 + h) ^ (rowb & 7)) << 4));
            }
            #pragma unroll
            for (int fr = 0; fr < 4; ++fr)
                #pragma unroll
                for (int fc = 0; fc < 2; ++fc)
                    acc[fr][fc] = __builtin_amdgcn_mfma_f32_16x16x32_bf16(
                        af[fr], bf[fc], acc[fr][fc], 0, 0, 0);
        }
        asm volatile("" ::: "memory");
        __builtin_amdgcn_s_barrier();
        asm volatile("" ::: "memory");
        buf ^= 1;
    }
    #undef GSTAGE

    const int mw = m0 + wr * 64;
    const int ob0 = bn0 + wc * 32;

    if (isK) {
        #pragma unroll
        for (int fc = 0; fc < 2; ++fc) {
            int o = ob0 + fc * 16 + r;
            float bs = bias[o];
            #pragma unroll
            for (int fr = 0; fr < 4; ++fr)
                #pragma unroll
                for (int rr = 0; rr < 4; ++rr) {
                    int mrow = mw + fr * 16 + h * 4 + rr;
                    Kb[(size_t)mrow * AD + o] = f2b((acc[fr][fc][rr] + bs));
                }
        }
    } else {
        u16* tile = (u16*)(smem + wave * 4608);
        #pragma unroll
        for (int fc = 0; fc < 2; ++fc) {
            int o = ob0 + fc * 16 + r;
            float bs = bias[o];
            #pragma unroll
            for (int fr = 0; fr < 4; ++fr) {
                u16x4 v4;
                #pragma unroll
                for (int rr = 0; rr < 4; ++rr) v4[rr] = f2b(acc[fr][fc][rr] + bs);
                *(u16x4*)(tile + (fc * 16 + r) * 72 + fr * 16 + h * 4) = v4;
            }
        }
        __builtin_amdgcn_s_waitcnt(0);
        int bb = mw >> 12, nb = mw & 4095;
        #pragma unroll
        for (int g = 0; g < 4; ++g) {
            int chunk = g * 64 + lane;
            int row = chunk >> 3, ns = chunk & 7;
            int ch = ob0 + row;
            int j = nb + ns * 8;
            bf16x8 val = *(const bf16x8*)(tile + row * 72 + ns * 8);
            size_t off = (size_t)bb * CU * NN + (size_t)(ch >> 5) * (NN * 32)
                       + (size_t)(j >> 4) * 512
                       + (size_t)((ch & 31) + ((j >> 3) & 1) * 32) * 8 + (j & 7);
            *(bf16x8*)(Vb + off) = val;
        }
    }
}

// ---------------- flash attention (round-19: 3-deep K pipeline) -------------
// 256 blocks x 768 thr (12 waves): waves 0-3 = QK (iw = w>>1, jw = w&1),
// waves 4-11 = PV (iw = pvid>>2, pj = (pvid>>1)&1, cgh = pvid&1, o[5]).
// LDS 117,248 B: kbuf 3x32K @0; pbuf 2 par x 8960 @98304; ml @116224.
// PV body: PV_BODY(i-1) first, then STAGE K[i+2] (newest VM ops -> never
// drained by V-use waits; full-iteration latency cover).
__global__ __launch_bounds__(768, 3) void attn_kernel(
        const u16* __restrict__ Q, const u16* __restrict__ K,
        const u16* __restrict__ V, u16* __restrict__ AO) {
    __shared__ __align__(16) char smem[117248];

    const int t = threadIdx.x;
    const int lane = t & 63;
    const int wave = t >> 6;          // 0..11
    const int r = lane & 31, hi = lane >> 5;

    int linear = blockIdx.x;
    int swz = (linear & 7) * 32 + (linear >> 3);
    int b = swz >> 6;
    int i0 = (swz & 63) * 64;

    const u16* Qb = Q + ((size_t)b * NN + i0) * AD;
    const u16* Kb = K + (size_t)b * NN * AD;
    const u16* Vb = V + (size_t)b * CU * NN;

    // ---- prologue: stage K[0] AND K[1] (4096 chunks) with all 768 threads ----
    {
        #pragma unroll
        for (int n = 0; n < 5; ++n) {
            int id = n * 768 + t;
            if (id < 4096) {
                int tile = id >> 11;
                int idx = id & 2047;
                int row = idx >> 5, c16 = idx & 31;
                async_cp16(Kb + tile * 16384 + row * 256 + ((c16 ^ (row & 31)) << 3),
                           smem + (unsigned)(n * 768 + (t & ~63)) * 16u);
            }
        }
        if (t < 256) {
            int id = 3840 + t;
            int tile = id >> 11;
            int idx = id & 2047;
            int row = idx >> 5, c16 = idx & 31;
            async_cp16(Kb + tile * 16384 + row * 256 + ((c16 ^ (row & 31)) << 3),
                       smem + (unsigned)(3840 + (t & ~63)) * 16u);
        }
    }
    asm volatile("s_waitcnt vmcnt(0)" ::: "memory");
    __builtin_amdgcn_s_barrier();     // K[0], K[1] ready
    asm volatile("" ::: "memory");

    if (wave < 4) {
        // ================= QK role =================
        const int iw = wave >> 1;
        const int jw = wave & 1;
        bf16x8 q[16];
        #pragma unroll
        for (int kk = 0; kk < 16; ++kk)
            q[kk] = *(const bf16x8*)(Qb + (size_t)(iw * 32 + r) * AD + kk * 16 + hi * 8);
        float m = -INFINITY, lsum = 0.0f;

        for (int i = 0; i < 64; ++i) {
            if (i) {
                __builtin_amdgcn_s_barrier();
                asm volatile("" ::: "memory");
            }
            const char* Kt = smem + (i % 3) * 32768 + jw * 16384;
            f32x16 sa = (f32x16)0.0f, sb = (f32x16)0.0f;
            __builtin_amdgcn_s_setprio(1);
            #pragma unroll
            for (int kk = 0; kk < 8; ++kk) {
                bf16x8 k0 = *(const bf16x8*)(Kt + r * 512 + (((2 * kk + hi) ^ r) << 4));
                bf16x8 k1 = *(const bf16x8*)(Kt + r * 512 + (((2 * (kk + 8) + hi) ^ r) << 4));
                sa = __builtin_amdgcn_mfma_f32_32x32x16_bf16(k0, q[kk], sa, 0, 0, 0);
                sb = __builtin_amdgcn_mfma_f32_32x32x16_bf16(k1, q[kk + 8], sb, 0, 0, 0);
            }
            __builtin_amdgcn_s_setprio(0);
            f32x16 s = sa + sb;

            float x0 = fmaxf(s[0], s[1]),   x1 = fmaxf(s[2], s[3]);
            float x2 = fmaxf(s[4], s[5]),   x3 = fmaxf(s[6], s[7]);
            float x4 = fmaxf(s[8], s[9]),   x5 = fmaxf(s[10], s[11]);
            float x6 = fmaxf(s[12], s[13]), x7 = fmaxf(s[14], s[15]);
            float pmax = fmaxf(fmaxf(fmaxf(x0, x1), fmaxf(x2, x3)),
                               fmaxf(fmaxf(x4, x5), fmaxf(x6, x7)));
            pmax = fmaxf(pmax, __shfl_xor(pmax, 32));
            char* pb = smem + 98304 + (i & 1) * 8960;
            int fl = __any(pmax > m + 8.0f) ? 1 : 0;
            if (fl) {
                float mn = fmaxf(m, pmax);
                float al = exp2_fast(m - mn);
                m = mn;
                lsum *= al;
                if (lane < 32) *(float*)(pb + 8192 + (iw * 2 + jw) * 128 + r * 4) = al;
            }
            if (lane == 0) *(int*)(pb + 8704 + (iw * 2 + jw) * 4) = fl;
            float p[16];
            #pragma unroll
            for (int e = 0; e < 16; ++e) p[e] = exp2_fast(s[e] - m);
            float y0 = (p[0] + p[1]) + (p[2] + p[3]);
            float y1 = (p[4] + p[5]) + (p[6] + p[7]);
            float y2 = (p[8] + p[9]) + (p[10] + p[11]);
            float y3 = (p[12] + p[13]) + (p[14] + p[15]);
            float ps = (y0 + y1) + (y2 + y3);
            ps += __shfl_xor(ps, 32);
            lsum += ps;

            #pragma unroll
            for (int ks = 0; ks < 2; ++ks) {
                unsigned a0 = cvt_pk_bf16(p[8 * ks + 0], p[8 * ks + 1]);
                unsigned a1 = cvt_pk_bf16(p[8 * ks + 2], p[8 * ks + 3]);
                unsigned b0 = cvt_pk_bf16(p[8 * ks + 4], p[8 * ks + 5]);
                unsigned b1 = cvt_pk_bf16(p[8 * ks + 6], p[8 * ks + 7]);
                asm("v_permlane32_swap_b32 %0, %1" : "+v"(a0), "+v"(b0));
                asm("v_permlane32_swap_b32 %0, %1" : "+v"(a1), "+v"(b1));
                union { unsigned w[4]; bf16x8 v; } u;
                u.w[0] = a0; u.w[1] = a1; u.w[2] = b0; u.w[3] = b1;
                *(bf16x8*)(pb + (iw * 2 + jw) * 2048 + ks * 1024 + lane * 16) = u.v;
            }
            asm volatile("s_waitcnt lgkmcnt(0)" ::: "memory");
            __builtin_amdgcn_sched_barrier(0);
        }
        __builtin_amdgcn_s_barrier();   // P(63) published
        asm volatile("" ::: "memory");
        if (lane < 32) {
            *(float*)(smem + 116224 + (iw * 2 + jw) * 128 + r * 4) = m;
            *(float*)(smem + 116224 + 512 + (iw * 2 + jw) * 128 + r * 4) = lsum;
        }
        __syncthreads();    // syncA
        __syncthreads();    // syncB
        __syncthreads();    // syncC
    } else {
        // ================= PV role =================
        const int pvid = wave - 4;          // 0..7
        const int iw = pvid >> 2;           // 32-row group
        const int pj = (pvid >> 1) & 1;     // which jw's P
        const int cgh = pvid & 1;           // 160-ch half
        const int tp = t - 256;             // 0..511 over waves 4-11

        int goffp[4];
        #pragma unroll
        for (int n = 0; n < 4; ++n) {
            int id = n * 512 + tp;
            int row = (id >> 5) & 63;
            int c16 = id & 31;
            goffp[n] = row * 256 + ((c16 ^ (row & 31)) << 3);
        }
        const unsigned wbp = (unsigned)(tp & ~63) * 16u;

        #define STAGE(BUF, KP) do {                                               \
            _Pragma("unroll")                                                     \
            for (int n_ = 0; n_ < 4; ++n_)                                        \
                async_cp16((KP) + goffp[n_],                                      \
                           smem + (BUF) * 32768 + n_ * 8192 + wbp);               \
        } while (0)

        f32x16 o[5];
        #pragma unroll
        for (int ct = 0; ct < 5; ++ct) o[ct] = (f32x16)0.0f;
        const u16* vb = Vb + (size_t)(cgh * 5) * 131072 + lane * 8;

        #define PV_BODY(TI) do {                                                  \
            const char* pb = smem + 98304 + ((TI) & 1) * 8960;                    \
            int fl = *(volatile const int*)(pb + 8704 + (iw * 2 + pj) * 4);       \
            bf16x8 pf0 = *(const bf16x8*)(pb + (iw * 2 + pj) * 2048 + lane * 16); \
            bf16x8 pf1 = *(const bf16x8*)(pb + (iw * 2 + pj) * 2048 + 1024 +      \
                                          lane * 16);                             \
            bf16x8 vfA[5], vfB[5];                                                \
            _Pragma("unroll")                                                     \
            for (int c = 0; c < 5; ++c)                                           \
                vfA[c] = *(const bf16x8*)(vb + (size_t)c * 131072 +               \
                                          ((TI) * 4 + pj * 2 + 0) * 512);         \
            _Pragma("unroll")                                                     \
            for (int c = 0; c < 5; ++c)                                           \
                vfB[c] = *(const bf16x8*)(vb + (size_t)c * 131072 +               \
                                          ((TI) * 4 + pj * 2 + 1) * 512);         \
            if (fl) {                                                             \
                float alv = *(volatile const float*)(pb + 8192 +                  \
                                (iw * 2 + pj) * 128 + (lane & 31) * 4);           \
                _Pragma("unroll")                                                 \
                for (int ct = 0; ct < 5; ++ct) o[ct] *= alv;                      \
            }                                                                     \
            __builtin_amdgcn_s_setprio(1);                                        \
            _Pragma("unroll")                                                     \
            for (int ct = 0; ct < 5; ++ct)                                        \
                o[ct] = __builtin_amdgcn_mfma_f32_32x32x16_bf16(vfA[ct], pf0,     \
                                                                o[ct], 0, 0, 0); \
            _Pragma("unroll")                                                     \
            for (int ct = 0; ct < 5; ++ct)                                        \
                o[ct] = __builtin_amdgcn_mfma_f32_32x32x16_bf16(vfB[ct], pf1,     \
                                                                o[ct], 0, 0, 0); \
            __builtin_amdgcn_s_setprio(0);                                        \
        } while (0)

        for (int i = 0; i < 64; ++i) {
            if (i) {
                __builtin_amdgcn_s_barrier();
                asm volatile("" ::: "memory");
            }
            if (i >= 1) PV_BODY(i - 1);
            if (i <= 61) {
                STAGE((i + 2) % 3, Kb + (i + 2) * 16384);
                asm volatile("s_waitcnt vmcnt(4)" ::: "memory");
            } else {
                asm volatile("s_waitcnt vmcnt(0)" ::: "memory");
            }
        }
        __builtin_amdgcn_s_barrier();   // P(63) published
        asm volatile("" ::: "memory");
        PV_BODY(63);

        __syncthreads();    // syncA: m/l published, kbuf dead
        float m0 = *(const float*)(smem + 116224 + (iw * 2 + pj) * 128 + r * 4);
        float l0 = *(const float*)(smem + 116224 + 512 + (iw * 2 + pj) * 128 + r * 4);
        float m1 = *(const float*)(smem + 116224 + (iw * 2 + (pj ^ 1)) * 128 + r * 4);
        float l1 = *(const float*)(smem + 116224 + 512 + (iw * 2 + (pj ^ 1)) * 128 + r * 4);
        float M = fmaxf(m0, m1);
        float fsc = exp2_fast(m0 - M);
        float fo = exp2_fast(m1 - M);
        float inv = 1.0f / (l0 * fsc + l1 * fo);

        u16* fb = (u16*)smem;              // [64][328] bf16, in-place merge
        if (pj == 1) {
            #pragma unroll
            for (int ct = 0; ct < 5; ++ct)
                #pragma unroll
                for (int e = 0; e < 16; ++e) {
                    int c = cgh * 160 + ct * 32 + (e & 3) + 8 * (e >> 2) + 4 * hi;
                    fb[(iw * 32 + r) * 328 + c] = f2b(o[ct][e] * fsc);
                }
        }
        __syncthreads();    // syncB
        if (pj == 0) {
            #pragma unroll
            for (int ct = 0; ct < 5; ++ct)
                #pragma unroll
                for (int g = 0; g < 4; ++g) {
                    int cb = cgh * 160 + ct * 32 + 8 * g + 4 * hi;
                    u16* fr = &fb[(iw * 32 + r) * 328 + cb];
                    float v0 = (o[ct][4 * g + 0] * fsc + b2f(fr[0])) * inv;
                    float v1 = (o[ct][4 * g + 1] * fsc + b2f(fr[1])) * inv;
                    float v2 = (o[ct][4 * g + 2] * fsc + b2f(fr[2])) * inv;
                    float v3 = (o[ct][4 * g + 3] * fsc + b2f(fr[3])) * inv;
                    *(unsigned*)(fr) = cvt_pk_bf16(v0, v1);
                    *(unsigned*)(fr + 2) = cvt_pk_bf16(v2, v3);
                }
        }
        __syncthreads();    // syncC
        #undef PV_BODY
        #undef STAGE
    }

    // ---- common: store AO (64 q-rows x 320 ch) from smem [64][328] ----
    const u16* ob = (const u16*)smem;
    u16* AOb = AO + ((size_t)b * NN + i0) * CU;
    #pragma unroll
    for (int n = 0; n < 3; ++n) {
        int id = n * 768 + t;
        int row = id / 40, c8 = id % 40;
        bf16x8 val = *(const bf16x8*)(ob + row * 328 + c8 * 8);
        *(bf16x8*)(AOb + (size_t)row * CU + c8 * 8) = val;
    }
    if (t < 256) {
        int id = 2304 + t;
        int row = id / 40, c8 = id % 40;
        bf16x8 val = *(const bf16x8*)(ob + row * 328 + c8 * 8);
        *(bf16x8*)(AOb + (size_t)row * CU + c8 * 8) = val;
    }
}

extern "C" void kernel_launch(void* const* d_in, const int* in_sizes, int n_in,
                              void* d_out, int out_size, void* d_ws, size_t ws_size,
                              hipStream_t stream) {
    const float* unet  = (const float*)d_in[0];
    const float* janus = (const float*)d_in[1];
    const float* Wq = (const float*)d_in[2];
    const float* bq = (const float*)d_in[3];
    const float* Wk = (const float*)d_in[4];
    const float* bk = (const float*)d_in[5];
    const float* Wv = (const float*)d_in[6];
    const float* bv = (const float*)d_in[7];
    const float* Wo = (const float*)d_in[8];
    const float* bo = (const float*)d_in[9];
    float* out = (float*)d_out;

    char* ws = (char*)d_ws;
    u16* Xu  = (u16*)(ws + XU_OFF);
    u16* Xj  = (u16*)(ws + XJ_OFF);
    u16* Qb  = (u16*)(ws + QB_OFF);
    u16* Kb  = (u16*)(ws + KB_OFF);
    u16* Vb  = (u16*)(ws + VB_OFF);
    u16* wq  = (u16*)(ws + WQ_OFF);
    u16* wk  = (u16*)(ws + WK_OFF);
    u16* wv  = (u16*)(ws + WV_OFF);
    u16* wo  = (u16*)(ws + WO_OFF);
    u16* AO  = (u16*)(ws + AO_OFF);

    // fused prep: transposes + weight cast
    prep_kernel<<<8400, 256, 0, stream>>>(unet, janus, Wq, Wk, Wv, Wo,
                                          Xu, Xj, wq, wk, wv, wo);

    // Q pre-scaled by (1/16) * log2(e) so softmax runs in exp2 domain
    gemm_kernel<0, 320, 256><<<dim3(64, 4), 512, 0, stream>>>(
        Xu, wq, bq, Qb, nullptr, 0.0901684411f);

    // fused K + V projections
    gemm_kv_kernel<<<dim3(64, 9), 512, 0, stream>>>(
        Xj, wk, wv, bk, bv, Kb, Vb);

    attn_kernel<<<256, 768, 0, stream>>>(Qb, Kb, Vb, AO);

    gemm_kernel<2, 320, 320><<<dim3(64, 5), 512, 0, stream>>>(
        AO, wo, bo, out, unet, 1.0f);
}